// Round 1
// baseline (540.416 us; speedup 1.0000x reference)
//
#include <hip/hip_runtime.h>
#include <math.h>

#define BB 2
#define LL 5
#define CC 256
#define HH 100
#define WW 252
#define HW (HH*WW)
#define CHW (CC*HW)
#define THRE_F 0.01f

// ---------------------------------------------------------------------------
// Kernel 1: confidence mask for odd agents only (even agents are forced to 1).
// m in [0,4): n = (m>>1)*LL + ((m&1)*2+1)  ->  n in {1,3,6,8}
// mask[m*HW + h*WW + w] = (gauss5x5(sigmoid(max_a psm[n,a])) > 0.01) ? 1 : 0
// ---------------------------------------------------------------------------
__global__ void mask_kernel(const float* __restrict__ psm, float* __restrict__ mask)
{
    int idx = blockIdx.x * blockDim.x + threadIdx.x;
    const int total = 4 * HW;
    if (idx >= total) return;
    int m = idx / HW;
    int p = idx - m * HW;
    int h = p / WW;
    int w = p - h * WW;
    int n = (m >> 1) * LL + ((m & 1) * 2 + 1);
    const float* base0 = psm + (size_t)n * 2 * HW;
    const float* base1 = base0 + HW;

    float acc = 0.0f;
#pragma unroll
    for (int i = 0; i < 5; ++i) {
        int yy = h + i - 2;
        if (yy < 0 || yy >= HH) continue;   // zero padding
#pragma unroll
        for (int j = 0; j < 5; ++j) {
            int xx = w + j - 2;
            if (xx < 0 || xx >= WW) continue;
            float v0 = base0[yy * WW + xx];
            float v1 = base1[yy * WW + xx];
            float v = fmaxf(v0, v1);
            float conf = 1.0f / (1.0f + expf(-v));     // sigmoid(max) == max(sigmoid)
            // gaussian weight, constant-folded per unrolled (i,j)
            double dx = (double)(j - 2), dy = (double)(i - 2);
            float g = (float)((1.0 / (2.0 * M_PI)) * exp(-0.5 * (dx * dx + dy * dy)));
            acc += g * conf;
        }
    }
    mask[idx] = (acc > THRE_F) ? 1.0f : 0.0f;
}

// ---------------------------------------------------------------------------
// Kernel 2: fused warp + mask + per-pixel attention fusion.
// Block = (b, h, w-tile of 64). 256 threads: wl = tid&63 (pixel), cg = tid>>6
// (channel group, c = cg,cg+4,...). Tap offsets/weights are channel-invariant:
// computed once into registers, reused for all 64 channel iterations.
// ---------------------------------------------------------------------------
__global__ __launch_bounds__(256) void fuse_kernel(
    const float* __restrict__ x,     // (B*L, C, H, W)
    const float* __restrict__ pt,    // (B, L, L, 4, 4)
    const float* __restrict__ mask,  // (4, H, W) odd-agent masks
    float* __restrict__ out)         // (B, C, H, W)
{
    int blk = blockIdx.x;                 // b*(H*4) + h*4 + wt
    int b   = blk / (HH * 4);
    int rem = blk - b * (HH * 4);
    int h   = rem >> 2;
    int wt  = rem & 3;

    int tid = threadIdx.x;
    int wl  = tid & 63;
    int cg  = tid >> 6;
    int w   = wt * 64 + wl;
    bool active = (w < WW);

    // normalized base coords (match affine_grid)
    float xsn = (w + 0.5f) * (2.0f / WW) - 1.0f;
    float ysn = (h + 0.5f) * (2.0f / HH) - 1.0f;

    int   off[LL][4];
    float wgt[LL][4];

#pragma unroll
    for (int l = 0; l < LL; ++l) {
        const float* M = pt + (size_t)(b * LL * LL + l) * 16;   // pairwise[b,0,l]
        float t00 = M[0];
        float t01 = M[1] * (100.0f / 252.0f);
        float t02 = M[3] / 403.2f * 2.0f;        // /(DOWNSAMPLE*VOXEL*W)*2
        float t10 = M[4] * (252.0f / 100.0f);
        float t11 = M[5];
        float t12 = M[7] / 160.0f * 2.0f;        // /(DOWNSAMPLE*VOXEL*H)*2

        float gx = t00 * xsn + t01 * ysn + t02;
        float gy = t10 * xsn + t11 * ysn + t12;
        float fx = ((gx + 1.0f) * WW - 1.0f) * 0.5f;
        float fy = ((gy + 1.0f) * HH - 1.0f) * 0.5f;
        float fx0 = floorf(fx), fy0 = floorf(fy);
        float wx1 = fx - fx0,  wy1 = fy - fy0;
        float wx0 = 1.0f - wx1, wy0 = 1.0f - wy1;
        int x0 = (int)fx0, y0 = (int)fy0;
        int x1 = x0 + 1,   y1 = y0 + 1;

        int cx0 = min(max(x0, 0), WW - 1), cx1 = min(max(x1, 0), WW - 1);
        int cy0 = min(max(y0, 0), HH - 1), cy1 = min(max(y1, 0), HH - 1);

        float vx0 = (x0 >= 0 && x0 < WW) ? 1.0f : 0.0f;
        float vx1 = (x1 >= 0 && x1 < WW) ? 1.0f : 0.0f;
        float vy0 = (y0 >= 0 && y0 < HH) ? 1.0f : 0.0f;
        float vy1 = (y1 >= 0 && y1 < HH) ? 1.0f : 0.0f;

        float m00 = 1.0f, m01 = 1.0f, m10 = 1.0f, m11 = 1.0f;
        if (l & 1) {   // odd agent: apply conv mask (read at clipped coords)
            const float* mb = mask + (size_t)(b * 2 + (l >> 1)) * HW;
            m00 = mb[cy0 * WW + cx0];
            m01 = mb[cy0 * WW + cx1];
            m10 = mb[cy1 * WW + cx0];
            m11 = mb[cy1 * WW + cx1];
        }

        float act = active ? 1.0f : 0.0f;
        wgt[l][0] = wx0 * wy0 * vx0 * vy0 * m00 * act;
        wgt[l][1] = wx1 * wy0 * vx1 * vy0 * m01 * act;
        wgt[l][2] = wx0 * wy1 * vx0 * vy1 * m10 * act;
        wgt[l][3] = wx1 * wy1 * vx1 * vy1 * m11 * act;

        int nbase = (b * LL + l) * CHW;
        off[l][0] = nbase + cy0 * WW + cx0;
        off[l][1] = nbase + cy0 * WW + cx1;
        off[l][2] = nbase + cy1 * WW + cx0;
        off[l][3] = nbase + cy1 * WW + cx1;
    }

    // ---- Phase 1: scores[l] = sum_c f0[c] * f_l[c], partial per cg ----
    float part[LL] = {0.f, 0.f, 0.f, 0.f, 0.f};
    for (int c = cg; c < CC; c += 4) {
        int coff = c * HW;
        float f0 = wgt[0][0] * x[off[0][0] + coff]
                 + wgt[0][1] * x[off[0][1] + coff]
                 + wgt[0][2] * x[off[0][2] + coff]
                 + wgt[0][3] * x[off[0][3] + coff];
        part[0] += f0 * f0;
#pragma unroll
        for (int l = 1; l < LL; ++l) {
            float fl = wgt[l][0] * x[off[l][0] + coff]
                     + wgt[l][1] * x[off[l][1] + coff]
                     + wgt[l][2] * x[off[l][2] + coff]
                     + wgt[l][3] * x[off[l][3] + coff];
            part[l] += f0 * fl;
        }
    }

    __shared__ float sred[4][LL][64];
#pragma unroll
    for (int l = 0; l < LL; ++l) sred[cg][l][wl] = part[l];
    __syncthreads();

    __shared__ float sattn[LL][64];
    if (tid < 64) {
        float sc[LL];
        float mx = -1e30f;
#pragma unroll
        for (int l = 0; l < LL; ++l) {
            float s = (sred[0][l][wl] + sred[1][l][wl]
                     + sred[2][l][wl] + sred[3][l][wl]) * 0.0625f;  // / sqrt(256)
            sc[l] = s;
            mx = fmaxf(mx, s);
        }
        float denom = 0.0f;
#pragma unroll
        for (int l = 0; l < LL; ++l) { sc[l] = expf(sc[l] - mx); denom += sc[l]; }
        float inv = 1.0f / denom;
#pragma unroll
        for (int l = 0; l < LL; ++l) sattn[l][wl] = sc[l] * inv;
    }
    __syncthreads();

    float a0 = sattn[0][wl], a1 = sattn[1][wl], a2 = sattn[2][wl],
          a3 = sattn[3][wl], a4 = sattn[4][wl];

    // ---- Phase 2: ctx[c] = sum_l attn_l * f_l[c] ----
    int obase = b * CHW + h * WW + w;
    for (int c = cg; c < CC; c += 4) {
        int coff = c * HW;
        float ctx;
        {
            float fl = wgt[0][0] * x[off[0][0] + coff]
                     + wgt[0][1] * x[off[0][1] + coff]
                     + wgt[0][2] * x[off[0][2] + coff]
                     + wgt[0][3] * x[off[0][3] + coff];
            ctx = a0 * fl;
        }
        {
            float fl = wgt[1][0] * x[off[1][0] + coff]
                     + wgt[1][1] * x[off[1][1] + coff]
                     + wgt[1][2] * x[off[1][2] + coff]
                     + wgt[1][3] * x[off[1][3] + coff];
            ctx += a1 * fl;
        }
        {
            float fl = wgt[2][0] * x[off[2][0] + coff]
                     + wgt[2][1] * x[off[2][1] + coff]
                     + wgt[2][2] * x[off[2][2] + coff]
                     + wgt[2][3] * x[off[2][3] + coff];
            ctx += a2 * fl;
        }
        {
            float fl = wgt[3][0] * x[off[3][0] + coff]
                     + wgt[3][1] * x[off[3][1] + coff]
                     + wgt[3][2] * x[off[3][2] + coff]
                     + wgt[3][3] * x[off[3][3] + coff];
            ctx += a3 * fl;
        }
        {
            float fl = wgt[4][0] * x[off[4][0] + coff]
                     + wgt[4][1] * x[off[4][1] + coff]
                     + wgt[4][2] * x[off[4][2] + coff]
                     + wgt[4][3] * x[off[4][3] + coff];
            ctx += a4 * fl;
        }
        if (active) out[obase + coff] = ctx;
    }
}

extern "C" void kernel_launch(void* const* d_in, const int* in_sizes, int n_in,
                              void* d_out, int out_size, void* d_ws, size_t ws_size,
                              hipStream_t stream)
{
    const float* x   = (const float*)d_in[0];   // (10, 256, 100, 252)
    const float* psm = (const float*)d_in[1];   // (10, 2, 100, 252)
    const float* pt  = (const float*)d_in[2];   // (2, 5, 5, 4, 4)
    // d_in[3] = record_len (unused by the output path)
    float* out  = (float*)d_out;                // (2, 256, 100, 252)
    float* mask = (float*)d_ws;                 // 4 * HW floats (~400 KB)

    {
        int total = 4 * HW;
        int blocks = (total + 255) / 256;
        mask_kernel<<<blocks, 256, 0, stream>>>(psm, mask);
    }
    {
        int blocks = BB * HH * 4;   // 800
        fuse_kernel<<<blocks, 256, 0, stream>>>(x, pt, mask, out);
    }
}

// Round 2
// 512.569 us; speedup vs baseline: 1.0543x; 1.0543x over previous
//
#include <hip/hip_runtime.h>
#include <math.h>

#define BB 2
#define LL 5
#define CC 256
#define HH 100
#define WW 252
#define HW (HH*WW)
#define CHW (CC*HW)
#define THRE_F 0.01f

// 5x5 gaussian, sigma=1:  g = 1/(2*pi) * exp(-(dx^2+dy^2)/2)  -- float literals,
// no runtime exp (the previous double-exp version risked f64 libcalls).
__device__ const float GW[5][5] = {
    {0.002915024f, 0.013064233f, 0.021539279f, 0.013064233f, 0.002915024f},
    {0.013064233f, 0.058549832f, 0.096532353f, 0.058549832f, 0.013064233f},
    {0.021539279f, 0.096532353f, 0.159154943f, 0.096532353f, 0.021539279f},
    {0.013064233f, 0.058549832f, 0.096532353f, 0.058549832f, 0.013064233f},
    {0.002915024f, 0.013064233f, 0.021539279f, 0.013064233f, 0.002915024f},
};

__device__ __forceinline__ float2 ld2(const float* p) {
    float2 v;
    __builtin_memcpy(&v, p, sizeof(float2));   // 4B-aligned-safe pair load
    return v;
}

// ---------------------------------------------------------------------------
// Kernel 1: confidence mask for odd agents (even agents are forced to 1).
// m in [0,4): n = (m>>1)*LL + ((m&1)*2+1)  ->  n in {1,3,6,8}
// ---------------------------------------------------------------------------
__global__ void mask_kernel(const float* __restrict__ psm, float* __restrict__ mask)
{
    int idx = blockIdx.x * blockDim.x + threadIdx.x;
    if (idx >= 4 * HW) return;
    int m = idx / HW;
    int p = idx - m * HW;
    int h = p / WW;
    int w = p - h * WW;
    int n = (m >> 1) * LL + ((m & 1) * 2 + 1);
    const float* base0 = psm + (size_t)n * 2 * HW;
    const float* base1 = base0 + HW;

    float acc = 0.0f;
#pragma unroll
    for (int i = 0; i < 5; ++i) {
        int yy = h + i - 2;
        if (yy < 0 || yy >= HH) continue;   // zero padding
#pragma unroll
        for (int j = 0; j < 5; ++j) {
            int xx = w + j - 2;
            if (xx < 0 || xx >= WW) continue;
            float v = fmaxf(base0[yy * WW + xx], base1[yy * WW + xx]);
            acc += GW[i][j] / (1.0f + __expf(-v));   // sigmoid(max)==max(sigmoid)
        }
    }
    mask[idx] = (acc > THRE_F) ? 1.0f : 0.0f;
}

// ---------------------------------------------------------------------------
// Per-(pixel, agent) bilinear tap setup. The two x-taps of a row are adjacent
// floats -> fetched as one float2 at bx = clamp(x0, 0, W-2); border shifts are
// folded into per-lane coefficients (a* multiplies .x, b* multiplies .y).
// Channel-invariant: computed once, reused for all channel iterations.
// ---------------------------------------------------------------------------
struct TapSetup {
    int   off0[LL], off1[LL];            // float2 base offsets, rows y0 / y1
    float a0[LL], b0[LL], a1[LL], b1[LL];
};

__device__ __forceinline__ void make_taps(
    int b, int h, int w, bool active, int c0,
    const float* __restrict__ pt, const float* __restrict__ mask, TapSetup& T)
{
    float xsn = (w + 0.5f) * (2.0f / WW) - 1.0f;
    float ysn = (h + 0.5f) * (2.0f / HH) - 1.0f;
    float act = active ? 1.0f : 0.0f;

#pragma unroll
    for (int l = 0; l < LL; ++l) {
        const float* M = pt + (size_t)(b * LL * LL + l) * 16;   // pairwise[b,0,l]
        float t00 = M[0];
        float t01 = M[1] * (100.0f / 252.0f);
        float t02 = M[3] / 403.2f * 2.0f;        // /(DOWNSAMPLE*VOXEL*W)*2
        float t10 = M[4] * (252.0f / 100.0f);
        float t11 = M[5];
        float t12 = M[7] / 160.0f * 2.0f;        // /(DOWNSAMPLE*VOXEL*H)*2

        float gx = t00 * xsn + t01 * ysn + t02;
        float gy = t10 * xsn + t11 * ysn + t12;
        float fx = ((gx + 1.0f) * WW - 1.0f) * 0.5f;
        float fy = ((gy + 1.0f) * HH - 1.0f) * 0.5f;
        float fx0 = floorf(fx), fy0 = floorf(fy);
        float wx1 = fx - fx0,  wy1 = fy - fy0;
        float wx0 = 1.0f - wx1, wy0 = 1.0f - wy1;
        int x0 = (int)fx0, y0 = (int)fy0;
        int x1 = x0 + 1,   y1 = y0 + 1;

        int cx0 = min(max(x0, 0), WW - 1), cx1 = min(max(x1, 0), WW - 1);
        int cy0 = min(max(y0, 0), HH - 1), cy1 = min(max(y1, 0), HH - 1);

        float vx0 = (x0 >= 0 && x0 < WW) ? 1.0f : 0.0f;
        float vx1 = (x1 >= 0 && x1 < WW) ? 1.0f : 0.0f;
        float vy0 = (y0 >= 0 && y0 < HH) ? 1.0f : 0.0f;
        float vy1 = (y1 >= 0 && y1 < HH) ? 1.0f : 0.0f;

        float m00 = 1.0f, m01 = 1.0f, m10 = 1.0f, m11 = 1.0f;
        if (l & 1) {   // odd agent: gaussian-conf mask at clipped coords
            const float* mb = mask + (size_t)(b * 2 + (l >> 1)) * HW;
            m00 = mb[cy0 * WW + cx0];
            m01 = mb[cy0 * WW + cx1];
            m10 = mb[cy1 * WW + cx0];
            m11 = mb[cy1 * WW + cx1];
        }

        float w00 = wx0 * wy0 * vx0 * vy0 * m00 * act;
        float w01 = wx1 * wy0 * vx1 * vy0 * m01 * act;
        float w10 = wx0 * wy1 * vx0 * vy1 * m10 * act;
        float w11 = wx1 * wy1 * vx1 * vy1 * m11 * act;

        int bx = min(max(x0, 0), WW - 2);
        int d  = x0 - bx;                 // -1, 0, or 1 near borders (else 0)
        T.a0[l] = (d == 0 ? w00 : 0.0f) + (d == -1 ? w01 : 0.0f);
        T.b0[l] = (d == 0 ? w01 : 0.0f) + (d ==  1 ? w00 : 0.0f);
        T.a1[l] = (d == 0 ? w10 : 0.0f) + (d == -1 ? w11 : 0.0f);
        T.b1[l] = (d == 0 ? w11 : 0.0f) + (d ==  1 ? w10 : 0.0f);

        int nbase = (b * LL + l) * CHW + c0 * HW;
        T.off0[l] = nbase + cy0 * WW + bx;
        T.off1[l] = nbase + cy1 * WW + bx;
    }
}

// ---------------------------------------------------------------------------
// Kernel 2: partial attention scores. Block = (b, h, wtile, cchunk of 128 ch).
// 256 thr: wl=pixel lane, cg=channel subgroup (32 ch each). Grid 1600 blocks.
// scoresP layout: [chunk][b][l][HW]  (every slot written -> no init needed)
// ---------------------------------------------------------------------------
__global__ __launch_bounds__(256) void score_kernel(
    const float* __restrict__ x, const float* __restrict__ pt,
    const float* __restrict__ mask, float* __restrict__ scoresP)
{
    int blk = blockIdx.x;
    int cc = blk & 1;
    int t  = blk >> 1;
    int wt = t & 3; t >>= 2;
    int h  = t % HH;
    int b  = t / HH;

    int tid = threadIdx.x;
    int wl  = tid & 63;
    int cg  = tid >> 6;
    int w   = wt * 64 + wl;
    bool active = (w < WW);
    int c0 = cc * 128 + cg * 32;

    TapSetup T;
    make_taps(b, h, w, active, c0, pt, mask, T);

    float s[LL] = {0.f, 0.f, 0.f, 0.f, 0.f};
    for (int i = 0; i < 32; ++i) {
        float2 r0[LL], r1[LL];
#pragma unroll
        for (int l = 0; l < LL; ++l) {
            r0[l] = ld2(x + T.off0[l]);
            r1[l] = ld2(x + T.off1[l]);
        }
        float f0 = T.a0[0] * r0[0].x + T.b0[0] * r0[0].y
                 + T.a1[0] * r1[0].x + T.b1[0] * r1[0].y;
        s[0] += f0 * f0;
#pragma unroll
        for (int l = 1; l < LL; ++l) {
            float fl = T.a0[l] * r0[l].x + T.b0[l] * r0[l].y
                     + T.a1[l] * r1[l].x + T.b1[l] * r1[l].y;
            s[l] += f0 * fl;
        }
#pragma unroll
        for (int l = 0; l < LL; ++l) { T.off0[l] += HW; T.off1[l] += HW; }
    }

    __shared__ float sred[4][LL][64];
#pragma unroll
    for (int l = 0; l < LL; ++l) sred[cg][l][wl] = s[l];
    __syncthreads();

    if (tid < 64 && active) {
        int p = h * WW + w;
#pragma unroll
        for (int l = 0; l < LL; ++l) {
            float v = sred[0][l][wl] + sred[1][l][wl]
                    + sred[2][l][wl] + sred[3][l][wl];
            scoresP[((cc * BB + b) * LL + l) * HW + p] = v;
        }
    }
}

// ---------------------------------------------------------------------------
// Kernel 3: softmax over L (recomputed per thread, cheap) + weighted gather.
// Attention weights folded into the tap coefficients -> inner loop is 10
// float2 loads + 20 FMAs + 1 store per channel.
// ---------------------------------------------------------------------------
__global__ __launch_bounds__(256) void out_kernel(
    const float* __restrict__ x, const float* __restrict__ pt,
    const float* __restrict__ mask, const float* __restrict__ scoresP,
    float* __restrict__ out)
{
    int blk = blockIdx.x;
    int cc = blk & 1;
    int t  = blk >> 1;
    int wt = t & 3; t >>= 2;
    int h  = t % HH;
    int b  = t / HH;

    int tid = threadIdx.x;
    int wl  = tid & 63;
    int cg  = tid >> 6;
    int w   = wt * 64 + wl;
    bool active = (w < WW);
    int c0 = cc * 128 + cg * 32;

    float a[LL];
    if (active) {
        int p = h * WW + w;
        float mx = -1e30f;
#pragma unroll
        for (int l = 0; l < LL; ++l) {
            float v = (scoresP[(b * LL + l) * HW + p]
                     + scoresP[((BB + b) * LL + l) * HW + p]) * 0.0625f; // /sqrt(256)
            a[l] = v;
            mx = fmaxf(mx, v);
        }
        float denom = 0.0f;
#pragma unroll
        for (int l = 0; l < LL; ++l) { a[l] = expf(a[l] - mx); denom += a[l]; }
        float inv = 1.0f / denom;
#pragma unroll
        for (int l = 0; l < LL; ++l) a[l] *= inv;
    } else {
#pragma unroll
        for (int l = 0; l < LL; ++l) a[l] = 0.0f;
    }

    TapSetup T;
    make_taps(b, h, w, active, c0, pt, mask, T);
#pragma unroll
    for (int l = 0; l < LL; ++l) {   // fold attn into coefficients
        T.a0[l] *= a[l]; T.b0[l] *= a[l]; T.a1[l] *= a[l]; T.b1[l] *= a[l];
    }

    int obase = b * CHW + c0 * HW + h * WW + w;
    for (int i = 0; i < 32; ++i) {
        float2 r0[LL], r1[LL];
#pragma unroll
        for (int l = 0; l < LL; ++l) {
            r0[l] = ld2(x + T.off0[l]);
            r1[l] = ld2(x + T.off1[l]);
        }
        float ctx = 0.0f;
#pragma unroll
        for (int l = 0; l < LL; ++l) {
            ctx += T.a0[l] * r0[l].x + T.b0[l] * r0[l].y
                 + T.a1[l] * r1[l].x + T.b1[l] * r1[l].y;
        }
        if (active) out[obase + i * HW] = ctx;
#pragma unroll
        for (int l = 0; l < LL; ++l) { T.off0[l] += HW; T.off1[l] += HW; }
    }
}

extern "C" void kernel_launch(void* const* d_in, const int* in_sizes, int n_in,
                              void* d_out, int out_size, void* d_ws, size_t ws_size,
                              hipStream_t stream)
{
    const float* x   = (const float*)d_in[0];   // (10, 256, 100, 252)
    const float* psm = (const float*)d_in[1];   // (10, 2, 100, 252)
    const float* pt  = (const float*)d_in[2];   // (2, 5, 5, 4, 4)
    float* out = (float*)d_out;                 // (2, 256, 100, 252)

    float* maskw  = (float*)d_ws;               // 4*HW floats  (~400 KB)
    float* scores = maskw + 4 * HW;             // 2*B*L*HW floats (~2 MB)

    mask_kernel<<<(4 * HW + 255) / 256, 256, 0, stream>>>(psm, maskw);
    score_kernel<<<BB * HH * 4 * 2, 256, 0, stream>>>(x, pt, maskw, scores);
    out_kernel<<<BB * HH * 4 * 2, 256, 0, stream>>>(x, pt, maskw, scores, out);
}

// Round 3
// 501.635 us; speedup vs baseline: 1.0773x; 1.0218x over previous
//
#include <hip/hip_runtime.h>
#include <math.h>

#define BB 2
#define LL 5
#define CC 256
#define HH 100
#define WW 252
#define HW (HH*WW)
#define CHW (CC*HW)
#define THRE_F 0.01f

typedef float v2f __attribute__((ext_vector_type(2)));
typedef float v4f __attribute__((ext_vector_type(4)));

__device__ __forceinline__ v2f ld2v(const float* p) {
    v2f v; __builtin_memcpy(&v, p, 8); return v;
}
__device__ __forceinline__ v4f ld4v(const float* p) {
    v4f v; __builtin_memcpy(&v, p, 16); return v;
}
__device__ __forceinline__ void st2v(float* p, v2f v) {
    __builtin_memcpy(p, &v, 8);
}
__device__ __forceinline__ float dot8(const float* c, v4f A, v4f B) {
    return c[0]*A.x + c[1]*A.y + c[2]*A.z + c[3]*A.w
         + c[4]*B.x + c[5]*B.y + c[6]*B.z + c[7]*B.w;
}

// 5x5 gaussian, sigma=1 (float literals, no runtime exp)
__device__ const float GW[5][5] = {
    {0.002915024f, 0.013064233f, 0.021539279f, 0.013064233f, 0.002915024f},
    {0.013064233f, 0.058549832f, 0.096532353f, 0.058549832f, 0.013064233f},
    {0.021539279f, 0.096532353f, 0.159154943f, 0.096532353f, 0.021539279f},
    {0.013064233f, 0.058549832f, 0.096532353f, 0.058549832f, 0.013064233f},
    {0.002915024f, 0.013064233f, 0.021539279f, 0.013064233f, 0.002915024f},
};

// ---------------------------------------------------------------------------
// Kernel 1: confidence mask for odd agents. m in [0,4): n in {1,3,6,8}
// ---------------------------------------------------------------------------
__global__ void mask_kernel(const float* __restrict__ psm, float* __restrict__ mask)
{
    int idx = blockIdx.x * blockDim.x + threadIdx.x;
    if (idx >= 4 * HW) return;
    int m = idx / HW;
    int p = idx - m * HW;
    int h = p / WW;
    int w = p - h * WW;
    int n = (m >> 1) * LL + ((m & 1) * 2 + 1);
    const float* base0 = psm + (size_t)n * 2 * HW;
    const float* base1 = base0 + HW;

    float acc = 0.0f;
#pragma unroll
    for (int i = 0; i < 5; ++i) {
        int yy = h + i - 2;
        if (yy < 0 || yy >= HH) continue;
#pragma unroll
        for (int j = 0; j < 5; ++j) {
            int xx = w + j - 2;
            if (xx < 0 || xx >= WW) continue;
            float v = fmaxf(base0[yy * WW + xx], base1[yy * WW + xx]);
            acc += GW[i][j] / (1.0f + __expf(-v));
        }
    }
    mask[idx] = (acc > THRE_F) ? 1.0f : 0.0f;
}

// ---------------------------------------------------------------------------
// Transform decode (theta row pair, pre-scaled per reference)
// ---------------------------------------------------------------------------
struct XF { float t00, t01, t02, t10, t11, t12; };

__device__ __forceinline__ XF load_xf(const float* __restrict__ pt, int b, int l) {
    const float* M = pt + (size_t)(b * LL * LL + l) * 16;  // pairwise[b,0,l]
    XF X;
    X.t00 = M[0];
    X.t01 = M[1] * (100.0f / 252.0f);
    X.t02 = M[3] / 403.2f * 2.0f;
    X.t10 = M[4] * (252.0f / 100.0f);
    X.t11 = M[5];
    X.t12 = M[7] / 160.0f * 2.0f;
    return X;
}
__device__ __forceinline__ bool is_trans(const XF& X) {
    return X.t00 == 1.0f && X.t01 == 0.0f && X.t10 == 0.0f && X.t11 == 1.0f;
}

// ---------------------------------------------------------------------------
// Translation fast-path tap setup for one agent l: lane owns pixels px0,px0+1.
// One 4-float window at even col covers all x-taps of both pixels; borders,
// validity, conv-mask and tile-activity folded into cf[16]:
//   cf[px*8 + row*4 + e]  multiplies window element e of row (y0,y1).
// ---------------------------------------------------------------------------
__device__ __forceinline__ void setup_trans(
    int l, int b, int h, int px0, float act, const XF& X,
    const float* __restrict__ maskw, int cstart,
    float cf[16], int o2[2])
{
    float tx = X.t02 * (WW * 0.5f);
    float ty = X.t12 * (HH * 0.5f);
    int ix = (int)floorf(tx);
    int iy = (int)floorf(ty);
    float wx1 = tx - (float)ix, wx0 = 1.0f - wx1;
    float wy1 = ty - (float)iy, wy0 = 1.0f - wy1;
    int y0 = h + iy, y1 = y0 + 1;
    int cy0 = min(max(y0, 0), HH - 1), cy1 = min(max(y1, 0), HH - 1);
    float vy0 = (y0 >= 0 && y0 < HH) ? 1.0f : 0.0f;
    float vy1 = (y1 >= 0 && y1 < HH) ? 1.0f : 0.0f;

    int craw = px0 + ix;
    int col = craw & ~1;
    col = min(max(col, 0), WW - 4);
    int d = craw - col;          // <= 3 (may be negative at left border)

    const float* mb = nullptr;
    if (l & 1) mb = maskw + (size_t)(b * 2 + (l >> 1)) * HW;

#pragma unroll
    for (int k = 0; k < 16; ++k) cf[k] = 0.0f;
#pragma unroll
    for (int px = 0; px < 2; ++px) {
#pragma unroll
        for (int r = 0; r < 2; ++r) {
#pragma unroll
            for (int t = 0; t < 2; ++t) {
                int xt = craw + px + t;
                float vx  = (xt >= 0 && xt < WW) ? 1.0f : 0.0f;
                float wcol = t ? wx1 : wx0;
                float wrow = r ? wy1 : wy0;
                float vyw  = r ? vy1 : vy0;
                float m = 1.0f;
                if (mb) {
                    int cx = min(max(xt, 0), WW - 1);
                    int cy = r ? cy1 : cy0;
                    m = mb[cy * WW + cx];
                }
                float wgt = wcol * wrow * vyw * vx * m * act;
                int e = d + px + t;
#pragma unroll
                for (int k = 0; k < 4; ++k)
                    if (e == k) cf[px * 8 + r * 4 + k] += wgt;
            }
        }
    }
    int nbase = (b * LL + l) * CHW + cstart * HW;
    o2[0] = nbase + cy0 * WW + col;
    o2[1] = nbase + cy1 * WW + col;
}

// ---------------------------------------------------------------------------
// General-affine tap setup (fallback; not exercised by translation inputs).
// Per pixel px: float2 loads at rows y0/y1, coefs gc[px*4 + {a0,b0,a1,b1}].
// ---------------------------------------------------------------------------
__device__ __forceinline__ void setup_gen(
    int l, int b, int h, int px0, float act, const XF& X,
    const float* __restrict__ maskw, int cstart,
    float gc[8], int o4[4])
{
    const float* mb = nullptr;
    if (l & 1) mb = maskw + (size_t)(b * 2 + (l >> 1)) * HW;
    float ysn = (h + 0.5f) * (2.0f / HH) - 1.0f;
    int nbase = (b * LL + l) * CHW + cstart * HW;

#pragma unroll
    for (int px = 0; px < 2; ++px) {
        float xsn = (px0 + px + 0.5f) * (2.0f / WW) - 1.0f;
        float gx = X.t00 * xsn + X.t01 * ysn + X.t02;
        float gy = X.t10 * xsn + X.t11 * ysn + X.t12;
        float fx = ((gx + 1.0f) * WW - 1.0f) * 0.5f;
        float fy = ((gy + 1.0f) * HH - 1.0f) * 0.5f;
        float fx0 = floorf(fx), fy0 = floorf(fy);
        float wx1 = fx - fx0, wy1 = fy - fy0;
        float wx0 = 1.0f - wx1, wy0 = 1.0f - wy1;
        int x0 = (int)fx0, y0 = (int)fy0;
        int x1 = x0 + 1, y1 = y0 + 1;
        int cx0 = min(max(x0, 0), WW - 1), cx1 = min(max(x1, 0), WW - 1);
        int cy0 = min(max(y0, 0), HH - 1), cy1 = min(max(y1, 0), HH - 1);
        float vx0 = (x0 >= 0 && x0 < WW) ? 1.0f : 0.0f;
        float vx1 = (x1 >= 0 && x1 < WW) ? 1.0f : 0.0f;
        float vy0 = (y0 >= 0 && y0 < HH) ? 1.0f : 0.0f;
        float vy1 = (y1 >= 0 && y1 < HH) ? 1.0f : 0.0f;
        float m00 = 1, m01 = 1, m10 = 1, m11 = 1;
        if (mb) {
            m00 = mb[cy0 * WW + cx0]; m01 = mb[cy0 * WW + cx1];
            m10 = mb[cy1 * WW + cx0]; m11 = mb[cy1 * WW + cx1];
        }
        float w00 = wx0 * wy0 * vx0 * vy0 * m00 * act;
        float w01 = wx1 * wy0 * vx1 * vy0 * m01 * act;
        float w10 = wx0 * wy1 * vx0 * vy1 * m10 * act;
        float w11 = wx1 * wy1 * vx1 * vy1 * m11 * act;
        int bx = min(max(x0, 0), WW - 2);
        int dd = x0 - bx;
        gc[px * 4 + 0] = (dd == 0 ? w00 : 0.f) + (dd == -1 ? w01 : 0.f);
        gc[px * 4 + 1] = (dd == 0 ? w01 : 0.f) + (dd ==  1 ? w00 : 0.f);
        gc[px * 4 + 2] = (dd == 0 ? w10 : 0.f) + (dd == -1 ? w11 : 0.f);
        gc[px * 4 + 3] = (dd == 0 ? w11 : 0.f) + (dd ==  1 ? w10 : 0.f);
        o4[px * 2 + 0] = nbase + cy0 * WW + bx;
        o4[px * 2 + 1] = nbase + cy1 * WW + bx;
    }
}

// ---------------------------------------------------------------------------
// Kernel 2: partial attention scores.
// Block = (b, h, wtile of 128 px, cchunk of 128 c). 256 thr = 4 cg x 64 lanes,
// each lane owns 2 adjacent pixels -> 1 KB contiguous per stream access.
// ---------------------------------------------------------------------------
__global__ __launch_bounds__(256) void score_kernel(
    const float* __restrict__ x, const float* __restrict__ pt,
    const float* __restrict__ maskw, float* __restrict__ scoresP)
{
    int blk = blockIdx.x;
    int cc = blk & 1;
    int wt = (blk >> 1) & 1;
    int t  = blk >> 2;
    int h  = t % HH;
    int b  = t / HH;

    int tid = threadIdx.x;
    int lane = tid & 63;
    int cg   = tid >> 6;
    int px0  = wt * 128 + 2 * lane;
    float act = (px0 < WW) ? 1.0f : 0.0f;
    v2f act2 = {act, act};
    int cstart = cc * 128 + cg * 32;

    XF X[LL];
#pragma unroll
    for (int l = 0; l < LL; ++l) X[l] = load_xf(pt, b, l);
    bool ident0 = is_trans(X[0]) && X[0].t02 == 0.0f && X[0].t12 == 0.0f;
    bool ftrans = ident0 && is_trans(X[1]) && is_trans(X[2])
                         && is_trans(X[3]) && is_trans(X[4]);

    v2f s[LL];
#pragma unroll
    for (int l = 0; l < LL; ++l) s[l] = (v2f){0.f, 0.f};

    if (ftrans) {
        int f0off = b * LL * CHW + cstart * HW + h * WW + min(px0, WW - 2);
        float cf[4][16];
        int o[8];
#pragma unroll
        for (int l = 1; l < LL; ++l)
            setup_trans(l, b, h, px0, act, X[l], maskw, cstart, cf[l - 1], &o[(l - 1) * 2]);

        for (int ci = 0; ci < 32; ++ci) {
            v2f f0 = ld2v(x + f0off) * act2;  f0off += HW;
            s[0] += f0 * f0;
#pragma unroll
            for (int l = 1; l < LL; ++l) {
                v4f F0 = ld4v(x + o[(l - 1) * 2 + 0]);
                v4f F1 = ld4v(x + o[(l - 1) * 2 + 1]);
                o[(l - 1) * 2 + 0] += HW;
                o[(l - 1) * 2 + 1] += HW;
                v2f fl;
                fl.x = dot8(&cf[l - 1][0], F0, F1);
                fl.y = dot8(&cf[l - 1][8], F0, F1);
                s[l] += f0 * fl;
            }
        }
    } else {
        float gc[LL][8];
        int go[LL][4];
#pragma unroll
        for (int l = 0; l < LL; ++l)
            setup_gen(l, b, h, px0, act, X[l], maskw, cstart, gc[l], go[l]);

        for (int ci = 0; ci < 32; ++ci) {
            v2f fv[LL];
#pragma unroll
            for (int l = 0; l < LL; ++l) {
                v2f R00 = ld2v(x + go[l][0]);
                v2f R01 = ld2v(x + go[l][1]);
                v2f R10 = ld2v(x + go[l][2]);
                v2f R11 = ld2v(x + go[l][3]);
#pragma unroll
                for (int k = 0; k < 4; ++k) go[l][k] += HW;
                fv[l].x = gc[l][0]*R00.x + gc[l][1]*R00.y + gc[l][2]*R01.x + gc[l][3]*R01.y;
                fv[l].y = gc[l][4]*R10.x + gc[l][5]*R10.y + gc[l][6]*R11.x + gc[l][7]*R11.y;
            }
#pragma unroll
            for (int l = 0; l < LL; ++l) s[l] += fv[0] * fv[l];
        }
    }

    __shared__ v2f sred[4][LL][64];
#pragma unroll
    for (int l = 0; l < LL; ++l) sred[cg][l][lane] = s[l];
    __syncthreads();

    if (tid < 64 && px0 < WW) {
        int p = h * WW + px0;
#pragma unroll
        for (int l = 0; l < LL; ++l) {
            v2f v = (sred[0][l][lane] + sred[1][l][lane]
                   + sred[2][l][lane] + sred[3][l][lane]) * 0.0625f;  // /sqrt(256)
            st2v(&scoresP[((cc * BB + b) * LL + l) * HW + p], v);
        }
    }
}

// ---------------------------------------------------------------------------
// Kernel 3: softmax over L (per thread from score partials) + weighted gather.
// Attention folded into tap coefficients.
// ---------------------------------------------------------------------------
__global__ __launch_bounds__(256) void out_kernel(
    const float* __restrict__ x, const float* __restrict__ pt,
    const float* __restrict__ maskw, const float* __restrict__ scoresP,
    float* __restrict__ out)
{
    int blk = blockIdx.x;
    int cc = blk & 1;
    int wt = (blk >> 1) & 1;
    int t  = blk >> 2;
    int h  = t % HH;
    int b  = t / HH;

    int tid = threadIdx.x;
    int lane = tid & 63;
    int cg   = tid >> 6;
    int px0  = wt * 128 + 2 * lane;
    float act = (px0 < WW) ? 1.0f : 0.0f;
    v2f act2 = {act, act};
    int cstart = cc * 128 + cg * 32;

    // softmax over agents, per pixel pair
    v2f a[LL];
    {
        int p = min(h * WW + px0, HW - 2);
        v2f mx = {-1e30f, -1e30f};
#pragma unroll
        for (int l = 0; l < LL; ++l) {
            v2f sc = ld2v(scoresP + (b * LL + l) * HW + p)
                   + ld2v(scoresP + ((BB + b) * LL + l) * HW + p);
            a[l] = sc;
            mx.x = fmaxf(mx.x, sc.x);
            mx.y = fmaxf(mx.y, sc.y);
        }
        v2f denom = {0.f, 0.f};
#pragma unroll
        for (int l = 0; l < LL; ++l) {
            a[l].x = __expf(a[l].x - mx.x);
            a[l].y = __expf(a[l].y - mx.y);
            denom += a[l];
        }
        v2f inv = {1.0f / denom.x, 1.0f / denom.y};
#pragma unroll
        for (int l = 0; l < LL; ++l) a[l] *= inv;
    }

    XF X[LL];
#pragma unroll
    for (int l = 0; l < LL; ++l) X[l] = load_xf(pt, b, l);
    bool ident0 = is_trans(X[0]) && X[0].t02 == 0.0f && X[0].t12 == 0.0f;
    bool ftrans = ident0 && is_trans(X[1]) && is_trans(X[2])
                         && is_trans(X[3]) && is_trans(X[4]);

    int obase = b * CHW + cstart * HW + h * WW + px0;
    bool doStore = (px0 < WW);

    if (ftrans) {
        int f0off = b * LL * CHW + cstart * HW + h * WW + min(px0, WW - 2);
        float cf[4][16];
        int o[8];
#pragma unroll
        for (int l = 1; l < LL; ++l) {
            setup_trans(l, b, h, px0, act, X[l], maskw, cstart, cf[l - 1], &o[(l - 1) * 2]);
#pragma unroll
            for (int k = 0; k < 8; ++k) {           // fold attn per pixel
                cf[l - 1][k]     *= a[l].x;
                cf[l - 1][k + 8] *= a[l].y;
            }
        }
        v2f af0 = a[0] * act2;

        for (int ci = 0; ci < 32; ++ci) {
            v2f f0 = ld2v(x + f0off);  f0off += HW;
            v2f ctx = af0 * f0;
#pragma unroll
            for (int l = 1; l < LL; ++l) {
                v4f F0 = ld4v(x + o[(l - 1) * 2 + 0]);
                v4f F1 = ld4v(x + o[(l - 1) * 2 + 1]);
                o[(l - 1) * 2 + 0] += HW;
                o[(l - 1) * 2 + 1] += HW;
                ctx.x += dot8(&cf[l - 1][0], F0, F1);
                ctx.y += dot8(&cf[l - 1][8], F0, F1);
            }
            if (doStore) st2v(&out[obase], ctx);
            obase += HW;
        }
    } else {
        float gc[LL][8];
        int go[LL][4];
#pragma unroll
        for (int l = 0; l < LL; ++l) {
            setup_gen(l, b, h, px0, act, X[l], maskw, cstart, gc[l], go[l]);
#pragma unroll
            for (int k = 0; k < 4; ++k) {
                gc[l][k]     *= a[l].x;
                gc[l][k + 4] *= a[l].y;
            }
        }
        for (int ci = 0; ci < 32; ++ci) {
            v2f ctx = {0.f, 0.f};
#pragma unroll
            for (int l = 0; l < LL; ++l) {
                v2f R00 = ld2v(x + go[l][0]);
                v2f R01 = ld2v(x + go[l][1]);
                v2f R10 = ld2v(x + go[l][2]);
                v2f R11 = ld2v(x + go[l][3]);
#pragma unroll
                for (int k = 0; k < 4; ++k) go[l][k] += HW;
                ctx.x += gc[l][0]*R00.x + gc[l][1]*R00.y + gc[l][2]*R01.x + gc[l][3]*R01.y;
                ctx.y += gc[l][4]*R10.x + gc[l][5]*R10.y + gc[l][6]*R11.x + gc[l][7]*R11.y;
            }
            if (doStore) st2v(&out[obase], ctx);
            obase += HW;
        }
    }
}

extern "C" void kernel_launch(void* const* d_in, const int* in_sizes, int n_in,
                              void* d_out, int out_size, void* d_ws, size_t ws_size,
                              hipStream_t stream)
{
    const float* x   = (const float*)d_in[0];   // (10, 256, 100, 252)
    const float* psm = (const float*)d_in[1];   // (10, 2, 100, 252)
    const float* pt  = (const float*)d_in[2];   // (2, 5, 5, 4, 4)
    float* out = (float*)d_out;                 // (2, 256, 100, 252)

    float* maskw  = (float*)d_ws;               // 4*HW floats
    float* scores = maskw + 4 * HW;             // 2*B*L*HW floats

    mask_kernel<<<(4 * HW + 255) / 256, 256, 0, stream>>>(psm, maskw);
    score_kernel<<<BB * HH * 2 * 2, 256, 0, stream>>>(x, pt, maskw, scores);
    out_kernel<<<BB * HH * 2 * 2, 256, 0, stream>>>(x, pt, maskw, scores, out);
}